// Round 10
// baseline (345.426 us; speedup 1.0000x reference)
//
#include <hip/hip_runtime.h>
#include <hip/hip_fp16.h>
#include <math.h>

#define BLK 256
#define CBSH 9           // 512 nodes per coarse bucket (196 buckets for n=100k)
#define CBN 512
#define NCBC 256         // static LDS sizing (nbkt <= 256)
#define NB2 512          // blocks for count/scatter passes

__device__ __forceinline__ float selu_f(float x) {
    const float kScale = 1.0507009873554805f;
    const float kAlpha = 1.6732632423543772f;
    return x > 0.0f ? kScale * x : kScale * kAlpha * expm1f(x);
}

__device__ __forceinline__ float2 h2f2(unsigned u) {
    __half2 h = *reinterpret_cast<__half2*>(&u);
    return __half22float2(h);
}
__device__ __forceinline__ void h8_set(float* a, uint4 v) {
    float2 f0 = h2f2(v.x), f1 = h2f2(v.y), f2 = h2f2(v.z), f3 = h2f2(v.w);
    a[0] = f0.x; a[1] = f0.y; a[2] = f1.x; a[3] = f1.y;
    a[4] = f2.x; a[5] = f2.y; a[6] = f3.x; a[7] = f3.y;
}
__device__ __forceinline__ void h8_add(float* a, uint4 v) {
    float2 f0 = h2f2(v.x), f1 = h2f2(v.y), f2 = h2f2(v.z), f3 = h2f2(v.w);
    a[0] += f0.x; a[1] += f0.y; a[2] += f1.x; a[3] += f1.y;
    a[4] += f2.x; a[5] += f2.y; a[6] += f3.x; a[7] += f3.y;
}
__device__ __forceinline__ uint4 f8_pack(const float* a) {
    __half2 h0 = __float22half2_rn(make_float2(a[0], a[1]));
    __half2 h1 = __float22half2_rn(make_float2(a[2], a[3]));
    __half2 h2 = __float22half2_rn(make_float2(a[4], a[5]));
    __half2 h3 = __float22half2_rn(make_float2(a[6], a[7]));
    uint4 u;
    u.x = *reinterpret_cast<unsigned*>(&h0);
    u.y = *reinterpret_cast<unsigned*>(&h1);
    u.z = *reinterpret_cast<unsigned*>(&h2);
    u.w = *reinterpret_cast<unsigned*>(&h3);
    return u;
}

// ---------------- CSR build (two-pass counting sort, unchanged) ----------------
__global__ void k_cnt(const int* __restrict__ dst, int* __restrict__ H, int e, int nbkt) {
    __shared__ int hist[NCBC];
    int tid = threadIdx.x;
    for (int b = tid; b < nbkt; b += BLK) hist[b] = 0;
    __syncthreads();
    int per = (e + NB2 - 1) / NB2;
    int lo = blockIdx.x * per;
    int hi = min(e, lo + per);
    for (int i = lo + tid; i < hi; i += BLK) atomicAdd(&hist[dst[i] >> CBSH], 1);
    __syncthreads();
    for (int b = tid; b < nbkt; b += BLK) H[blockIdx.x * nbkt + b] = hist[b];
}

__global__ void k_bsum(const int* __restrict__ H, int* __restrict__ bstart, int nbkt, int e) {
    __shared__ int tot[NCBC];
    int tid = threadIdx.x;
    for (int b = tid; b < nbkt; b += BLK) {
        int s = 0;
        for (int i = 0; i < NB2; ++i) s += H[i * nbkt + b];
        tot[b] = s;
    }
    __syncthreads();
    if (tid == 0) {
        int acc = 0;
        for (int b = 0; b < nbkt; ++b) {
            bstart[b] = acc;
            acc += tot[b];
        }
        bstart[nbkt] = acc;  // == e
    }
}

__global__ void k_off(int* __restrict__ H, const int* __restrict__ bstart, int nbkt) {
    __shared__ int lds[BLK];
    int b = blockIdx.x, tid = threadIdx.x;
    int v0 = H[(2 * tid) * nbkt + b];
    int v1 = H[(2 * tid + 1) * nbkt + b];
    int pair = v0 + v1;
    lds[tid] = pair;
    __syncthreads();
    int val = pair;
    for (int off = 1; off < BLK; off <<= 1) {
        int t2 = (tid >= off) ? lds[tid - off] : 0;
        __syncthreads();
        val += t2;
        lds[tid] = val;
        __syncthreads();
    }
    int excl = val - pair + bstart[b];
    H[(2 * tid) * nbkt + b] = excl;
    H[(2 * tid + 1) * nbkt + b] = excl + v0;
}

__global__ void k_scatter2(const int* __restrict__ src, const int* __restrict__ dst,
                           const int* __restrict__ H, unsigned* __restrict__ slab,
                           int e, int nbkt) {
    __shared__ int cur[NCBC];
    int tid = threadIdx.x;
    for (int b = tid; b < nbkt; b += BLK) cur[b] = H[blockIdx.x * nbkt + b];
    __syncthreads();
    int per = (e + NB2 - 1) / NB2;
    int lo = blockIdx.x * per;
    int hi = min(e, lo + per);
    for (int i = lo + tid; i < hi; i += BLK) {
        int s = src[i], d = dst[i];
        int b = d >> CBSH;
        int pos = atomicAdd(&cur[b], 1);
        slab[pos] = ((unsigned)s << CBSH) | (unsigned)(d & (CBN - 1));
    }
}

__global__ void k_build(const int* __restrict__ bstart, const unsigned* __restrict__ slab,
                        int* __restrict__ rowptr, float* __restrict__ dinv,
                        int* __restrict__ csr, int n, int e) {
    __shared__ int hist[CBN];
    __shared__ int stmp[BLK];
    int b = blockIdx.x, tid = threadIdx.x;
    hist[2 * tid] = 0;
    hist[2 * tid + 1] = 0;
    __syncthreads();
    int lo = bstart[b], hi = bstart[b + 1];
    for (int i = lo + tid; i < hi; i += BLK) atomicAdd(&hist[slab[i] & (CBN - 1)], 1);
    __syncthreads();
    int h0 = hist[2 * tid], h1 = hist[2 * tid + 1];
    int pair = h0 + h1;
    stmp[tid] = pair;
    __syncthreads();
    int val = pair;
    for (int off = 1; off < BLK; off <<= 1) {
        int t2 = (tid >= off) ? stmp[tid - off] : 0;
        __syncthreads();
        val += t2;
        stmp[tid] = val;
        __syncthreads();
    }
    int e0 = lo + val - pair;
    int e1 = e0 + h0;
    hist[2 * tid] = e0;
    hist[2 * tid + 1] = e1;
    int node0 = b << CBSH;
    int nA = node0 + 2 * tid, nB = nA + 1;
    if (nA < n) { rowptr[nA] = e0; dinv[nA] = rsqrtf((float)(h0 + 1)); }
    if (nB < n) { rowptr[nB] = e1; dinv[nB] = rsqrtf((float)(h1 + 1)); }
    if (b == 0 && tid == 0) rowptr[n] = e;
    __syncthreads();
    for (int i = lo + tid; i < hi; i += BLK) {
        unsigned p = slab[i];
        int pos = atomicAdd(&hist[p & (CBN - 1)], 1);
        csr[pos] = (int)(p >> CBSH);
    }
}

// ---------------- layer compute ----------------
// G layout everywhere: chunk-SoA [chunk][N] of uint4 (8 fp16). A: [chunk][N][8] fp32.

// gemm1: hs1 = dinv * (X @ W1), 15 cols -> 2 chunks fp16.
__global__ void k_gemm1(const float* __restrict__ x, const float* __restrict__ W,
                        const float* __restrict__ dinv, uint4* __restrict__ G, int n) {
    int i = blockIdx.x * BLK + threadIdx.x;
    if (i >= n) return;
    const float* xr = x + (size_t)i * 128;
    float acc[16];
#pragma unroll
    for (int f = 0; f < 16; ++f) acc[f] = 0.0f;
#pragma unroll
    for (int k4 = 0; k4 < 32; ++k4) {
        float4 xv = *reinterpret_cast<const float4*>(xr + k4 * 4);
        float xs[4] = {xv.x, xv.y, xv.z, xv.w};
#pragma unroll
        for (int j = 0; j < 4; ++j) {
            int k = k4 * 4 + j;
#pragma unroll
            for (int f = 0; f < 15; ++f) acc[f] = fmaf(xs[j], W[k * 15 + f], acc[f]);
        }
    }
    float di = dinv[i];
#pragma unroll
    for (int f = 0; f < 15; ++f) acc[f] *= di;
    acc[15] = 0.0f;
    G[i] = f8_pack(acc);
    G[(size_t)n + i] = f8_pack(acc + 8);
}

// agg layer1 (output-space) + fused G2 epilogue: one lane per node, chunk = bid&1.
__global__ void k_aggF(const int* __restrict__ rowptr, const int* __restrict__ csr,
                       const uint4* __restrict__ hs, uint4* __restrict__ G2,
                       const float* __restrict__ dinv, const float* __restrict__ bias, int n) {
    int chunk = blockIdx.x & 1;
    int d = (blockIdx.x >> 1) * BLK + threadIdx.x;
    if (d >= n) return;
    const uint4* gs = hs + (size_t)chunk * n;
    float a0[8], a1[8] = {0};
    h8_set(a0, gs[d]);  // self
    int p = rowptr[d], end = rowptr[d + 1];
    for (; p + 4 <= end; p += 4) {
        int r0 = csr[p], r1 = csr[p + 1], r2 = csr[p + 2], r3 = csr[p + 3];
        uint4 v0 = gs[r0], v1 = gs[r1], v2 = gs[r2], v3 = gs[r3];
        h8_add(a0, v0); h8_add(a1, v1); h8_add(a0, v2); h8_add(a1, v3);
    }
    for (; p < end; ++p) h8_add(a0, gs[csr[p]]);
    float di = dinv[d];
    float g[8];
    int colb = chunk * 8;
#pragma unroll
    for (int j = 0; j < 8; ++j) {
        int col = colb + j;
        float s = a0[j] + a1[j];
        g[j] = (col < 15) ? di * selu_f(di * s + bias[col]) : 0.0f;
    }
    G2[(size_t)chunk * n + d] = f8_pack(g);
}

// agg input-space: A_c[d] = G_c[d] + sum G_c[src].  chunk = bid & (CHM-1) -> XCD-private slice.
template <int CHM, int FCH>
__global__ void k_aggK(const int* __restrict__ rowptr, const int* __restrict__ csr,
                       const uint4* __restrict__ G, float4* __restrict__ A, int n) {
    int chunk = blockIdx.x & (CHM - 1);
    int d = (blockIdx.x / CHM) * BLK + threadIdx.x;
    if (d >= n) return;
    if (FCH < CHM && chunk >= FCH) return;
    const uint4* gs = G + (size_t)chunk * n;
    float a0[8], a1[8] = {0};
    h8_set(a0, gs[d]);  // self
    int p = rowptr[d], end = rowptr[d + 1];
    for (; p + 4 <= end; p += 4) {
        int r0 = csr[p], r1 = csr[p + 1], r2 = csr[p + 2], r3 = csr[p + 3];
        uint4 v0 = gs[r0], v1 = gs[r1], v2 = gs[r2], v3 = gs[r3];
        h8_add(a0, v0); h8_add(a1, v1); h8_add(a0, v2); h8_add(a1, v3);
    }
    for (; p < end; ++p) h8_add(a0, gs[csr[p]]);
    size_t o = ((size_t)chunk * n + d) * 2;
    A[o] = make_float4(a0[0] + a1[0], a0[1] + a1[1], a0[2] + a1[2], a0[3] + a1[3]);
    A[o + 1] = make_float4(a0[4] + a1[4], a0[5] + a1[5], a0[6] + a1[6], a0[7] + a1[7]);
}

// mid gemm: Gnext = dinv * selu(dinv*(A @ W) + b), fp16 chunk-SoA out.
template <int KCH, int K, int F, int FCH>
__global__ void k_gemmM(const float* __restrict__ A, const float* __restrict__ W,
                        const float* __restrict__ bias, const float* __restrict__ dinv,
                        uint4* __restrict__ G, int n) {
    int i = blockIdx.x * BLK + threadIdx.x;
    if (i >= n) return;
    const float4* A4 = reinterpret_cast<const float4*>(A);
    float xr[KCH * 8];
#pragma unroll
    for (int c = 0; c < KCH; ++c) {
        size_t o = ((size_t)c * n + i) * 2;
        float4 lo = A4[o], hi = A4[o + 1];
        xr[c * 8 + 0] = lo.x; xr[c * 8 + 1] = lo.y; xr[c * 8 + 2] = lo.z; xr[c * 8 + 3] = lo.w;
        xr[c * 8 + 4] = hi.x; xr[c * 8 + 5] = hi.y; xr[c * 8 + 6] = hi.z; xr[c * 8 + 7] = hi.w;
    }
    float acc[F];
#pragma unroll
    for (int f = 0; f < F; ++f) acc[f] = 0.0f;
#pragma unroll
    for (int k = 0; k < K; ++k)
#pragma unroll
        for (int f = 0; f < F; ++f) acc[f] = fmaf(xr[k], W[k * F + f], acc[f]);
    float di = dinv[i];
    float g[FCH * 8];
#pragma unroll
    for (int idx = 0; idx < FCH * 8; ++idx)
        g[idx] = (idx < F) ? di * selu_f(di * acc[idx] + bias[idx]) : 0.0f;
#pragma unroll
    for (int c = 0; c < FCH; ++c) G[(size_t)c * n + i] = f8_pack(g + c * 8);
}

// final gemm: out = selu(dinv*(A @ W4) + b4) -> d_out [N][36] fp32.
__global__ void k_gemm4(const float* __restrict__ A, const float* __restrict__ W,
                        const float* __restrict__ bias, const float* __restrict__ dinv,
                        float* __restrict__ out, int n) {
    int i = blockIdx.x * BLK + threadIdx.x;
    if (i >= n) return;
    const float4* A4 = reinterpret_cast<const float4*>(A);
    float xr[32];
#pragma unroll
    for (int c = 0; c < 4; ++c) {
        size_t o = ((size_t)c * n + i) * 2;
        float4 lo = A4[o], hi = A4[o + 1];
        xr[c * 8 + 0] = lo.x; xr[c * 8 + 1] = lo.y; xr[c * 8 + 2] = lo.z; xr[c * 8 + 3] = lo.w;
        xr[c * 8 + 4] = hi.x; xr[c * 8 + 5] = hi.y; xr[c * 8 + 6] = hi.z; xr[c * 8 + 7] = hi.w;
    }
    float acc[36];
#pragma unroll
    for (int f = 0; f < 36; ++f) acc[f] = 0.0f;
#pragma unroll
    for (int k = 0; k < 27; ++k)
#pragma unroll
        for (int f = 0; f < 36; ++f) acc[f] = fmaf(xr[k], W[k * 36 + f], acc[f]);
    float di = dinv[i];
    float r[36];
#pragma unroll
    for (int f = 0; f < 36; ++f) r[f] = selu_f(di * acc[f] + bias[f]);
    float* op = out + (size_t)i * 36;
#pragma unroll
    for (int f4 = 0; f4 < 9; ++f4)
        *reinterpret_cast<float4*>(op + f4 * 4) =
            make_float4(r[f4 * 4], r[f4 * 4 + 1], r[f4 * 4 + 2], r[f4 * 4 + 3]);
}

extern "C" void kernel_launch(void* const* d_in, const int* in_sizes, int n_in,
                              void* d_out, int out_size, void* d_ws, size_t ws_size,
                              hipStream_t stream) {
    const float* x = (const float*)d_in[0];
    const int* ei = (const int*)d_in[1];  // int32 on device
    const float* W1 = (const float*)d_in[2];
    const float* b1 = (const float*)d_in[3];
    const float* W2 = (const float*)d_in[4];
    const float* b2 = (const float*)d_in[5];
    const float* W3 = (const float*)d_in[6];
    const float* b3 = (const float*)d_in[7];
    const float* W4 = (const float*)d_in[8];
    const float* b4 = (const float*)d_in[9];

    int n = in_sizes[0] / 128;
    int e = in_sizes[1] / 2;
    const int* s32 = ei;
    const int* d32 = ei + e;
    int nbkt = (n + CBN - 1) >> CBSH;  // 196 for n=100k

    char* w = (char*)d_ws;
    auto alloc = [&](size_t bytes) {
        char* p = w;
        w += (bytes + 255) & ~(size_t)255;
        return p;
    };
    int* rowptr = (int*)alloc(((size_t)n + 1) * 4);
    float* dinv = (float*)alloc((size_t)n * 4);
    int* csr = (int*)alloc((size_t)e * 4);
    int* H = (int*)alloc((size_t)NB2 * nbkt * 4);
    int* bstart = (int*)alloc(((size_t)nbkt + 1) * 4);
    uint4* Gu1 = (uint4*)alloc((size_t)n * 4 * 16);  // 4 chunks fp16; aliases slab
    uint4* Gu2 = (uint4*)alloc((size_t)n * 4 * 16);
    float* A = (float*)alloc((size_t)n * 4 * 8 * 4); // 4 chunks fp32
    unsigned* slab = (unsigned*)Gu1;                 // e*4 = 6.4MB <= 6.4MB

    int nb = (n + BLK - 1) / BLK;     // 391
    int nbn = nb;

    // CSR build
    k_cnt<<<NB2, BLK, 0, stream>>>(d32, H, e, nbkt);
    k_bsum<<<1, BLK, 0, stream>>>(H, bstart, nbkt, e);
    k_off<<<nbkt, BLK, 0, stream>>>(H, bstart, nbkt);
    k_scatter2<<<NB2, BLK, 0, stream>>>(s32, d32, H, slab, e, nbkt);
    k_build<<<nbkt, BLK, 0, stream>>>(bstart, slab, rowptr, dinv, csr, n, e);

    // layer 1: gemm in F-space, agg in F-space with fused G2 epilogue
    k_gemm1<<<nb, BLK, 0, stream>>>(x, W1, dinv, Gu2, n);                 // hs1 -> Gu2 (2 chunks)
    k_aggF<<<2 * nbn, BLK, 0, stream>>>(rowptr, csr, Gu2, Gu1, dinv, b1, n);  // G2 -> Gu1

    // layer 2: agg G2 (K=15, 2 chunks) -> A2; gemm -> G3 (20 cols, 3 chunks)
    k_aggK<2, 2><<<2 * nbn, BLK, 0, stream>>>(rowptr, csr, Gu1, (float4*)A, n);
    k_gemmM<2, 15, 20, 3><<<nb, BLK, 0, stream>>>(A, W2, b2, dinv, Gu2, n);

    // layer 3: agg G3 (K=20, 3 chunks, CHM=4 w/ chunk3 idle) -> A3; gemm -> G4 (27 cols, 4 chunks)
    k_aggK<4, 3><<<4 * nbn, BLK, 0, stream>>>(rowptr, csr, Gu2, (float4*)A, n);
    k_gemmM<3, 20, 27, 4><<<nb, BLK, 0, stream>>>(A, W3, b3, dinv, Gu1, n);

    // layer 4: agg G4 (K=27, 4 chunks) -> A4; final gemm -> d_out
    k_aggK<4, 4><<<4 * nbn, BLK, 0, stream>>>(rowptr, csr, Gu1, (float4*)A, n);
    k_gemm4<<<nb, BLK, 0, stream>>>(A, W4, b4, dinv, (float*)d_out, n);
}